// Round 3
// baseline (476.958 us; speedup 1.0000x reference)
//
#include <hip/hip_runtime.h>

typedef unsigned short u16;
typedef unsigned short u16x8 __attribute__((ext_vector_type(8)));
typedef __bf16 bf16x8 __attribute__((ext_vector_type(8)));
typedef float f32x4 __attribute__((ext_vector_type(4)));

#define SEQQ 4096
#define HID 2048
#define HD 128
#define NBLK 64
#define ATT_SCALE 0.08838834764831843f

__device__ __forceinline__ u16 f2bf(float f) {
    unsigned u = __float_as_uint(f);
    u += 0x7fffu + ((u >> 16) & 1u);
    return (u16)(u >> 16);
}

__device__ __forceinline__ void gload_lds16(const void* g, void* l) {
    __builtin_amdgcn_global_load_lds((const __attribute__((address_space(1))) void*)g,
                                     (__attribute__((address_space(3))) void*)l, 16, 0, 0);
}

// ---------------- fp32 -> bf16 conversion ----------------
__global__ __launch_bounds__(256) void cvt_bf16_k(const float* __restrict__ in,
                                                  u16* __restrict__ out, int n4) {
    int i = blockIdx.x * 256 + threadIdx.x;
    if (i < n4) {
        float4 v = ((const float4*)in)[i];
        ushort4 o;
        o.x = f2bf(v.x); o.y = f2bf(v.y); o.z = f2bf(v.z); o.w = f2bf(v.w);
        ((ushort4*)out)[i] = o;
    }
}

__global__ __launch_bounds__(256) void cvt4_k(const float* __restrict__ w0,
                                              const float* __restrict__ w1,
                                              const float* __restrict__ w2,
                                              const float* __restrict__ w3,
                                              u16* __restrict__ qkv,
                                              u16* __restrict__ wo) {
    const int y = blockIdx.y;
    const float* src = (y == 0) ? w0 : (y == 1) ? w1 : (y == 2) ? w2 : w3;
    u16* dst = (y < 3) ? (qkv + (size_t)y * 4194304) : wo;
    int i = blockIdx.x * 256 + threadIdx.x;
    float4 v = ((const float4*)src)[i];
    ushort4 o;
    o.x = f2bf(v.x); o.y = f2bf(v.y); o.z = f2bf(v.z); o.w = f2bf(v.w);
    ((ushort4*)dst)[i] = o;
}

// ---------------- 256x256 BK=64 8-phase bf16 GEMM: C = A @ B^T ----------------
// MODE 0: f32 C row-major (width N).  MODE 1: QKV split, bf16 u16 outputs:
//   cols 0..2047 -> C0q, 2048..4095 -> C1, 4096..6143 -> C2 (all row-major [M][2048]).
// LDS k-group-major layout: conflict-free ds_read_b128, contiguous gload sources.
#define QUAD(MH, AF, BF)                                                        \
    __builtin_amdgcn_s_setprio(1);                                              \
    _Pragma("unroll") for (int mi = 0; mi < 4; ++mi) {                          \
        _Pragma("unroll") for (int ni = 0; ni < 4; ++ni)                        \
            acc[(MH) * 4 + mi][ni] = __builtin_amdgcn_mfma_f32_16x16x32_bf16(   \
                (AF)[mi], (BF)[ni], acc[(MH) * 4 + mi][ni], 0, 0, 0);           \
    }                                                                           \
    __builtin_amdgcn_s_setprio(0);

template <int MODE>
__global__ __launch_bounds__(512, 2) void gemm256(const u16* __restrict__ A,
                                                  const u16* __restrict__ B,
                                                  void* __restrict__ C0,
                                                  u16* __restrict__ C1,
                                                  u16* __restrict__ C2,
                                                  int M, int N, int K) {
    // [buf][khalf][kgroup][row][8]
    __shared__ __align__(16) u16 As[2][2][4][256][8];
    __shared__ __align__(16) u16 Bs[2][2][4][256][8];
    const int t = threadIdx.x, w = t >> 6, l = t & 63;
    const int wm = w >> 2, wn = w & 3, ll = l & 15, lg = l >> 4;

    const int gx = gridDim.x, gy = gridDim.y;
    const int nwg = gx * gy;
    int lid = blockIdx.y * gx + blockIdx.x;
    int swz = (lid & 7) * (nwg >> 3) + (lid >> 3);
    const int mb = swz % gy, nb = swz / gy;

    const int c1 = t, c2 = t + 512;
    const u16* gA1 = A + (size_t)(mb * 256 + (c1 & 255)) * K + (c1 >> 8) * 8;
    const u16* gA2 = A + (size_t)(mb * 256 + (c2 & 255)) * K + (c2 >> 8) * 8;
    const u16* gB1 = B + (size_t)(nb * 256 + (c1 & 255)) * K + (c1 >> 8) * 8;
    const u16* gB2 = B + (size_t)(nb * 256 + (c2 & 255)) * K + (c2 >> 8) * 8;

    f32x4 acc[8][4] = {};

    auto stageA = [&](int buf, int kh, int kt) {
        gload_lds16(gA1 + kt * 64 + kh * 32, &As[buf][kh][c1 >> 8][c1 & 255][0]);
        gload_lds16(gA2 + kt * 64 + kh * 32, &As[buf][kh][c2 >> 8][c2 & 255][0]);
    };
    auto stageB = [&](int buf, int kh, int kt) {
        gload_lds16(gB1 + kt * 64 + kh * 32, &Bs[buf][kh][c1 >> 8][c1 & 255][0]);
        gload_lds16(gB2 + kt * 64 + kh * 32, &Bs[buf][kh][c2 >> 8][c2 & 255][0]);
    };
    auto fragsA = [&](int buf, int kh, int mh, bf16x8* af) {
#pragma unroll
        for (int mi = 0; mi < 4; ++mi)
            af[mi] = *(const bf16x8*)&As[buf][kh][lg][wm * 128 + mh * 64 + mi * 16 + ll][0];
    };
    auto fragsB = [&](int buf, int kh, bf16x8* bf) {
#pragma unroll
        for (int ni = 0; ni < 4; ++ni)
            bf[ni] = *(const bf16x8*)&Bs[buf][kh][lg][wn * 64 + ni * 16 + ll][0];
    };

    // prologue: stage tile 0, wait first two half-tiles, leave k-half1 in flight
    stageA(0, 0, 0); stageB(0, 0, 0); stageA(0, 1, 0); stageB(0, 1, 0);
    asm volatile("s_waitcnt vmcnt(4)" ::: "memory");
    asm volatile("s_barrier" ::: "memory");

    const int T = K >> 6;
    for (int kt = 0; kt < T; ++kt) {
        const int buf = kt & 1, nbuf = buf ^ 1;
        const bool last = (kt == T - 1);
        bf16x8 a0[4], a1[4], b0[4];
        // P1: quadrant (kh0, m0-3)
        fragsA(buf, 0, 0, a0); fragsB(buf, 0, b0);
        if (!last) stageA(nbuf, 0, kt + 1);
        asm volatile("s_barrier" ::: "memory");
        QUAD(0, a0, b0)
        asm volatile("s_barrier" ::: "memory");
        // P2: (kh0, m4-7)
        fragsA(buf, 0, 1, a1);
        if (!last) {
            stageB(nbuf, 0, kt + 1);
            asm volatile("s_waitcnt vmcnt(4)" ::: "memory");  // kh1(t) landed
        } else {
            asm volatile("s_waitcnt vmcnt(0)" ::: "memory");
        }
        asm volatile("s_barrier" ::: "memory");
        QUAD(1, a1, b0)
        asm volatile("s_barrier" ::: "memory");
        // P3: (kh1, m0-3)
        fragsA(buf, 1, 0, a0); fragsB(buf, 1, b0);
        if (!last) stageA(nbuf, 1, kt + 1);
        asm volatile("s_barrier" ::: "memory");
        QUAD(0, a0, b0)
        asm volatile("s_barrier" ::: "memory");
        // P4: (kh1, m4-7)
        fragsA(buf, 1, 1, a1);
        if (!last) {
            stageB(nbuf, 1, kt + 1);
            asm volatile("s_waitcnt vmcnt(4)" ::: "memory");  // kh0(t+1) landed
        }
        asm volatile("s_barrier" ::: "memory");
        QUAD(1, a1, b0)
        asm volatile("s_barrier" ::: "memory");
    }

    // epilogue
    const int colb = nb * 256;
    u16* dstq = nullptr;
    int coff = 0;
    if (MODE == 1) {
        if (colb < 2048)      { dstq = (u16*)C0; coff = colb; }
        else if (colb < 4096) { dstq = C1; coff = colb - 2048; }
        else                  { dstq = C2; coff = colb - 4096; }
    }
#pragma unroll
    for (int mi = 0; mi < 8; ++mi)
#pragma unroll
        for (int ni = 0; ni < 4; ++ni) {
            f32x4 v = acc[mi][ni];
#pragma unroll
            for (int r = 0; r < 4; ++r) {
                int row = mb * 256 + wm * 128 + mi * 16 + lg * 4 + r;
                int col = wn * 64 + ni * 16 + ll;
                if (MODE == 0)
                    ((float*)C0)[(size_t)row * N + colb + col] = v[r];
                else
                    dstq[(size_t)row * 2048 + coff + col] = f2bf(v[r]);
            }
        }
}

// ---------------- bf16 transpose: in [4096][2048] -> out [2048][4096] ----------------
__global__ __launch_bounds__(256) void transpose_k(const u16* __restrict__ in,
                                                   u16* __restrict__ out) {
    __shared__ __align__(16) u16 tl[64][64];  // XOR-swizzled columns
    const int s0 = blockIdx.x * 64, d0 = blockIdx.y * 64;
    const int t = threadIdx.x;
#pragma unroll
    for (int j = 0; j < 2; ++j) {
        int c = j * 256 + t;
        int sr = c >> 3, c8 = c & 7;
        u16x8 v = *(const u16x8*)&in[(size_t)(s0 + sr) * 2048 + d0 + c8 * 8];
        *(u16x8*)&tl[sr][(c8 ^ (sr >> 3)) * 8] = v;
    }
    __syncthreads();
#pragma unroll
    for (int j = 0; j < 2; ++j) {
        int c = j * 256 + t;
        int dr = c >> 3, sg = c & 7;
        u16x8 v;
#pragma unroll
        for (int i = 0; i < 8; ++i)
            v[i] = tl[sg * 8 + i][(((dr >> 3) ^ sg) * 8) + (dr & 7)];
        *(u16x8*)&out[(size_t)(d0 + dr) * 4096 + s0 + sg * 8] = v;
    }
}

// ---------------- block-sparse attention (LDS-staged, double-buffered) ----------------
__global__ __launch_bounds__(256) void sparse_attn(const u16* __restrict__ Q,
                                                   const u16* __restrict__ Kmat,
                                                   const u16* __restrict__ Vt,
                                                   const int* __restrict__ rnd,
                                                   u16* __restrict__ Out) {
    __shared__ __align__(16) u16 Ks[2][8192];
    __shared__ __align__(16) u16 Vs[2][8192];
    __shared__ __align__(16) char Plds[4 * 2048];

    const int qb = blockIdx.x, h = blockIdx.y;
    const int t = threadIdx.x, w = t >> 6, l = t & 63;
    const int lg = l >> 4, ll = l & 15;

    int blist[6];
    int nblk = 0;
    {
        int cands[6];
        cands[0] = qb - 1; cands[1] = qb; cands[2] = qb + 1;
        cands[3] = 0; cands[4] = NBLK - 1; cands[5] = rnd[qb];
        for (int c = 0; c < 6; ++c) {
            int b = cands[c];
            if (b < 0 || b >= NBLK) continue;
            bool dup = false;
            for (int j = 0; j < nblk; ++j) dup = dup || (blist[j] == b);
            if (!dup) blist[nblk++] = b;
        }
    }

    auto stage = [&](int buf, int kb) {
        const u16* kbase = Kmat + (size_t)(kb * 64) * HID + h * HD;
        const u16* vbase = Vt + (size_t)(h * HD) * SEQQ + kb * 64;
#pragma unroll
        for (int j = 0; j < 4; ++j) {
            int d = j * 256 + t;
            int kr = d >> 4, kc_ = (d & 15) ^ (kr & 7);
            gload_lds16(kbase + (size_t)kr * HID + kc_ * 8, &Ks[buf][d * 8]);
            int vr = d >> 3, vc = (d & 7) ^ (vr & 7);
            gload_lds16(vbase + (size_t)vr * SEQQ + vc * 8, &Vs[buf][d * 8]);
        }
    };

    bf16x8 qf[4];
    const int qrow = qb * 64 + w * 16 + ll;
#pragma unroll
    for (int kc = 0; kc < 4; ++kc)
        qf[kc] = *(const bf16x8*)&Q[(size_t)qrow * HID + h * HD + kc * 32 + lg * 8];

    f32x4 o[8];
#pragma unroll
    for (int dt = 0; dt < 8; ++dt) o[dt] = (f32x4){0.f, 0.f, 0.f, 0.f};
    float mrun[4], lrun[4];
#pragma unroll
    for (int r = 0; r < 4; ++r) { mrun[r] = -1e30f; lrun[r] = 0.f; }

    char* Pw = Plds + w * 2048;

    stage(0, blist[0]);
    int cur = 0;

    for (int bi = 0; bi < nblk; ++bi) {
        if (bi + 1 < nblk) {
            stage(cur ^ 1, blist[bi + 1]);
            asm volatile("s_waitcnt vmcnt(8)\n\ts_barrier" ::: "memory");
        } else {
            asm volatile("s_waitcnt vmcnt(0)\n\ts_barrier" ::: "memory");
        }

        f32x4 s[4];
#pragma unroll
        for (int ct = 0; ct < 4; ++ct) s[ct] = (f32x4){0.f, 0.f, 0.f, 0.f};
#pragma unroll
        for (int ct = 0; ct < 4; ++ct) {
            const int krow = ct * 16 + ll;
#pragma unroll
            for (int kc = 0; kc < 4; ++kc) {
                bf16x8 kf = *(const bf16x8*)&Ks[cur][krow * 128 +
                                                    (((kc * 4 + lg) ^ (krow & 7)) << 3)];
                s[ct] = __builtin_amdgcn_mfma_f32_16x16x32_bf16(qf[kc], kf, s[ct], 0, 0, 0);
            }
        }

        float rmax[4];
#pragma unroll
        for (int r = 0; r < 4; ++r) {
            s[0][r] *= ATT_SCALE; s[1][r] *= ATT_SCALE;
            s[2][r] *= ATT_SCALE; s[3][r] *= ATT_SCALE;
            rmax[r] = fmaxf(fmaxf(s[0][r], s[1][r]), fmaxf(s[2][r], s[3][r]));
        }
#pragma unroll
        for (int mk = 1; mk <= 8; mk <<= 1)
#pragma unroll
            for (int r = 0; r < 4; ++r)
                rmax[r] = fmaxf(rmax[r], __shfl_xor(rmax[r], mk));

        float scl[4], psum[4];
#pragma unroll
        for (int r = 0; r < 4; ++r) {
            float mn = fmaxf(mrun[r], rmax[r]);
            scl[r] = __expf(mrun[r] - mn);
            mrun[r] = mn;
            psum[r] = 0.f;
        }

#pragma unroll
        for (int ct = 0; ct < 4; ++ct)
#pragma unroll
            for (int r = 0; r < 4; ++r) {
                float e = __expf(s[ct][r] - mrun[r]);
                psum[r] += e;
                const int q = lg * 4 + r;
                const int kv = ct * 16 + ll;
                *(u16*)(Pw + q * 128 + ((kv * 2) ^ ((q & 7) << 4))) = f2bf(e);
            }
#pragma unroll
        for (int mk = 1; mk <= 8; mk <<= 1)
#pragma unroll
            for (int r = 0; r < 4; ++r)
                psum[r] += __shfl_xor(psum[r], mk);
#pragma unroll
        for (int r = 0; r < 4; ++r)
            lrun[r] = lrun[r] * scl[r] + psum[r];
#pragma unroll
        for (int dt = 0; dt < 8; ++dt)
#pragma unroll
            for (int r = 0; r < 4; ++r)
                o[dt][r] *= scl[r];

#pragma unroll
        for (int kc2 = 0; kc2 < 2; ++kc2) {
            bf16x8 pf = *(const bf16x8*)(Pw + ll * 128 +
                                         ((kc2 * 64 + lg * 16) ^ ((ll & 7) << 4)));
#pragma unroll
            for (int dt = 0; dt < 8; ++dt) {
                const int vrow = dt * 16 + ll;
                bf16x8 vf = *(const bf16x8*)&Vs[cur][vrow * 64 +
                                                     (((kc2 * 4 + lg) ^ (vrow & 7)) << 3)];
                o[dt] = __builtin_amdgcn_mfma_f32_16x16x32_bf16(pf, vf, o[dt], 0, 0, 0);
            }
        }

        asm volatile("s_barrier" ::: "memory");
        cur ^= 1;
    }

    float rl[4];
#pragma unroll
    for (int r = 0; r < 4; ++r) rl[r] = 1.f / lrun[r];
#pragma unroll
    for (int dt = 0; dt < 8; ++dt)
#pragma unroll
        for (int r = 0; r < 4; ++r) {
            int row = qb * 64 + w * 16 + lg * 4 + r;
            int col = h * HD + dt * 16 + ll;
            Out[(size_t)row * HID + col] = f2bf(o[dt][r] * rl[r]);
        }
}

// ---------------- launcher ----------------
extern "C" void kernel_launch(void* const* d_in, const int* in_sizes, int n_in,
                              void* d_out, int out_size, void* d_ws, size_t ws_size,
                              hipStream_t stream) {
    const float* hs = (const float*)d_in[0];
    const int* rnd = (const int*)d_in[1];
    const float* Wq = (const float*)d_in[2];
    const float* Wk = (const float*)d_in[3];
    const float* Wv = (const float*)d_in[4];
    const float* Wo = (const float*)d_in[5];
    float* out = (float*)d_out;

    char* ws = (char*)d_ws;
    u16* hs_b   = (u16*)(ws);                  // 16 MB
    u16* Wqkv_b = (u16*)(ws + 16777216);       // 24 MB
    u16* Wo_b   = (u16*)(ws + 41943040);       //  8 MB
    u16* Qb     = (u16*)(ws + 50331648);       // 16 MB
    u16* Kb     = (u16*)(ws + 67108864);       // 16 MB
    u16* Vtb    = (u16*)(ws + 83886080);       // 16 MB ([2048][4096])
    u16* Ab     = (u16*)(ws + 100663296);      // 16 MB (Vrow temp, then attn out)

    cvt_bf16_k<<<dim3(8192), 256, 0, stream>>>(hs, hs_b, 8388608 / 4);
    cvt4_k<<<dim3(4096, 4), 256, 0, stream>>>(Wq, Wk, Wv, Wo, Wqkv_b, Wo_b);

    // fused QKV: C[4096,6144] = hs @ [Wq;Wk;Wv]^T -> Qb, Kb, Vrow(Ab)
    gemm256<1><<<dim3(24, 16), 512, 0, stream>>>(hs_b, Wqkv_b, Qb, Kb, Ab, 4096, 6144, 2048);

    transpose_k<<<dim3(64, 32), 256, 0, stream>>>(Ab, Vtb);

    sparse_attn<<<dim3(64, 16), 256, 0, stream>>>(Qb, Kb, Vtb, rnd, Ab);

    gemm256<0><<<dim3(8, 16), 512, 0, stream>>>(Ab, Wo_b, out, nullptr, nullptr, 4096, 2048, 2048);
}

// Round 4
// 437.538 us; speedup vs baseline: 1.0901x; 1.0901x over previous
//
#include <hip/hip_runtime.h>

typedef unsigned short u16;
typedef unsigned short u16x8 __attribute__((ext_vector_type(8)));
typedef __bf16 bf16x8 __attribute__((ext_vector_type(8)));
typedef float f32x4 __attribute__((ext_vector_type(4)));

#define SEQQ 4096
#define HID 2048
#define HD 128
#define NBLK 64
#define ATT_SCALE 0.08838834764831843f

__device__ __forceinline__ u16 f2bf(float f) {
    unsigned u = __float_as_uint(f);
    u += 0x7fffu + ((u >> 16) & 1u);
    return (u16)(u >> 16);
}

__device__ __forceinline__ void gload_lds16(const void* g, void* l) {
    __builtin_amdgcn_global_load_lds((const __attribute__((address_space(1))) void*)g,
                                     (__attribute__((address_space(3))) void*)l, 16, 0, 0);
}

// ---------------- fp32 -> bf16 conversion ----------------
__global__ __launch_bounds__(256) void cvt_bf16_k(const float* __restrict__ in,
                                                  u16* __restrict__ out, int n4) {
    int i = blockIdx.x * 256 + threadIdx.x;
    if (i < n4) {
        float4 v = ((const float4*)in)[i];
        ushort4 o;
        o.x = f2bf(v.x); o.y = f2bf(v.y); o.z = f2bf(v.z); o.w = f2bf(v.w);
        ((ushort4*)out)[i] = o;
    }
}

__global__ __launch_bounds__(256) void cvt4_k(const float* __restrict__ w0,
                                              const float* __restrict__ w1,
                                              const float* __restrict__ w2,
                                              const float* __restrict__ w3,
                                              u16* __restrict__ qkv,
                                              u16* __restrict__ wo) {
    const int y = blockIdx.y;
    const float* src = (y == 0) ? w0 : (y == 1) ? w1 : (y == 2) ? w2 : w3;
    u16* dst = (y < 3) ? (qkv + (size_t)y * 4194304) : wo;
    int i = blockIdx.x * 256 + threadIdx.x;
    float4 v = ((const float4*)src)[i];
    ushort4 o;
    o.x = f2bf(v.x); o.y = f2bf(v.y); o.z = f2bf(v.z); o.w = f2bf(v.w);
    ((ushort4*)dst)[i] = o;
}

// ------- 128x256 BK=64 triple-buffered pipelined bf16 GEMM: C = A @ B^T -------
// 8 waves, per-wave 64x64 output. LDS k-group-major (conflict-free ds_read_b128).
// Stage distance = 2 K-tiles (~5000 cyc); one vmcnt(6) per tile.
// MODE 0: f32 C row-major (N=2048). MODE 1: QKV split bf16 (BN=256 divides 2048).
template <int MODE>
__global__ __launch_bounds__(512, 2) void gemm_p(const u16* __restrict__ A,
                                                 const u16* __restrict__ B,
                                                 void* __restrict__ C0,
                                                 u16* __restrict__ C1,
                                                 u16* __restrict__ C2,
                                                 int M, int N, int K) {
    __shared__ __align__(16) u16 As[3][2][4][128][8];   // 48 KiB
    __shared__ __align__(16) u16 Bs[3][2][4][256][8];   // 96 KiB
    const int t = threadIdx.x, w = t >> 6, l = t & 63;
    const int ll = l & 15, lg = l >> 4;
    const int wm = w >> 2, wn = w & 3;

    // XCD swizzle: per-XCD contiguous band, nb-fast (A-panel 2MB resident in L2)
    const int gx = gridDim.x, gy = gridDim.y;
    const int per = (gx * gy) >> 3;
    int lid = blockIdx.y * gx + blockIdx.x;
    int virt = (lid & 7) * per + (lid >> 3);
    const int nb = virt % gx, mb = virt / gx;

    f32x4 acc[4][4] = {};

    const int akg = (t >> 7) & 3, arow = t & 127;
    const int bkg = t >> 8, brow = t & 255;
    const u16* gA = A + (size_t)(mb * 128 + arow) * K + akg * 8;
    const u16* gB = B + (size_t)(nb * 256 + brow) * K;

    auto stageA = [&](int sb, int kt) {
        const u16* p = gA + kt * 64;
        gload_lds16(p, &As[sb][0][akg][arow][0]);
        gload_lds16(p + 32, &As[sb][1][akg][arow][0]);
    };
    auto stageB = [&](int sb, int kt) {
        const u16* p = gB + kt * 64;
        gload_lds16(p + bkg * 8,        &Bs[sb][0][bkg][brow][0]);
        gload_lds16(p + (bkg + 2) * 8,  &Bs[sb][0][bkg + 2][brow][0]);
        gload_lds16(p + 32 + bkg * 8,   &Bs[sb][1][bkg][brow][0]);
        gload_lds16(p + 32 + (bkg + 2) * 8, &Bs[sb][1][bkg + 2][brow][0]);
    };

    // prologue: prime 2 tiles
    stageA(0, 0); stageB(0, 0); stageA(1, 1); stageB(1, 1);
    asm volatile("s_waitcnt vmcnt(6)" ::: "memory");
    __builtin_amdgcn_s_barrier();

    const int T = K >> 6;
    int buf = 0;
    for (int kt = 0; kt < T; ++kt) {
        const int sb = (buf + 2 >= 3) ? buf - 1 : buf + 2;
        const bool st = (kt + 2) < T;
        // ---- phase A (kh0) ----
        bf16x8 af[4], bfr[4];
#pragma unroll
        for (int mi = 0; mi < 4; ++mi)
            af[mi] = *(const bf16x8*)&As[buf][0][lg][wm * 64 + mi * 16 + ll][0];
#pragma unroll
        for (int ni = 0; ni < 4; ++ni)
            bfr[ni] = *(const bf16x8*)&Bs[buf][0][lg][wn * 64 + ni * 16 + ll][0];
        if (st) stageA(sb, kt + 2);
        __builtin_amdgcn_s_barrier();
        __builtin_amdgcn_s_setprio(1);
#pragma unroll
        for (int mi = 0; mi < 4; ++mi)
#pragma unroll
            for (int ni = 0; ni < 4; ++ni)
                acc[mi][ni] = __builtin_amdgcn_mfma_f32_16x16x32_bf16(af[mi], bfr[ni],
                                                                      acc[mi][ni], 0, 0, 0);
        __builtin_amdgcn_s_setprio(0);
        // ---- phase B (kh1) ----
        bf16x8 ag[4], bgr[4];
#pragma unroll
        for (int mi = 0; mi < 4; ++mi)
            ag[mi] = *(const bf16x8*)&As[buf][1][lg][wm * 64 + mi * 16 + ll][0];
#pragma unroll
        for (int ni = 0; ni < 4; ++ni)
            bgr[ni] = *(const bf16x8*)&Bs[buf][1][lg][wn * 64 + ni * 16 + ll][0];
        if (st) {
            stageB(sb, kt + 2);
            asm volatile("s_waitcnt vmcnt(6)" ::: "memory");  // tile kt+1 fully landed
        } else {
            asm volatile("s_waitcnt vmcnt(0)" ::: "memory");
        }
        __builtin_amdgcn_s_barrier();
        __builtin_amdgcn_s_setprio(1);
#pragma unroll
        for (int mi = 0; mi < 4; ++mi)
#pragma unroll
            for (int ni = 0; ni < 4; ++ni)
                acc[mi][ni] = __builtin_amdgcn_mfma_f32_16x16x32_bf16(ag[mi], bgr[ni],
                                                                      acc[mi][ni], 0, 0, 0);
        __builtin_amdgcn_s_setprio(0);
        __builtin_amdgcn_s_barrier();  // close tile: all reads of buf drained
        buf = (buf + 1 == 3) ? 0 : buf + 1;
    }

    // epilogue
    const int colb = nb * 256;
    u16* dstq = nullptr;
    int coff = 0;
    if (MODE == 1) {
        if (colb < 2048)      { dstq = (u16*)C0; coff = colb; }
        else if (colb < 4096) { dstq = C1; coff = colb - 2048; }
        else                  { dstq = C2; coff = colb - 4096; }
    }
#pragma unroll
    for (int mi = 0; mi < 4; ++mi)
#pragma unroll
        for (int ni = 0; ni < 4; ++ni) {
            f32x4 v = acc[mi][ni];
#pragma unroll
            for (int r = 0; r < 4; ++r) {
                int row = mb * 128 + wm * 64 + mi * 16 + lg * 4 + r;
                int col = wn * 64 + ni * 16 + ll;
                if (MODE == 0)
                    ((float*)C0)[(size_t)row * N + colb + col] = v[r];
                else
                    dstq[(size_t)row * 2048 + coff + col] = f2bf(v[r]);
            }
        }
}

// ---------------- bf16 transpose: in [4096][2048] -> out [2048][4096] ----------------
__global__ __launch_bounds__(256) void transpose_k(const u16* __restrict__ in,
                                                   u16* __restrict__ out) {
    __shared__ __align__(16) u16 tl[64][64];
    const int s0 = blockIdx.x * 64, d0 = blockIdx.y * 64;
    const int t = threadIdx.x;
#pragma unroll
    for (int j = 0; j < 2; ++j) {
        int c = j * 256 + t;
        int sr = c >> 3, c8 = c & 7;
        u16x8 v = *(const u16x8*)&in[(size_t)(s0 + sr) * 2048 + d0 + c8 * 8];
        *(u16x8*)&tl[sr][(c8 ^ (sr >> 3)) * 8] = v;
    }
    __syncthreads();
#pragma unroll
    for (int j = 0; j < 2; ++j) {
        int c = j * 256 + t;
        int dr = c >> 3, sg = c & 7;
        u16x8 v;
#pragma unroll
        for (int i = 0; i < 8; ++i)
            v[i] = tl[sg * 8 + i][(((dr >> 3) ^ sg) * 8) + (dr & 7)];
        *(u16x8*)&out[(size_t)(d0 + dr) * 4096 + s0 + sg * 8] = v;
    }
}

// ------- block-sparse attention: K triple-buffered in LDS, V reg-prefetched -------
__global__ __launch_bounds__(256) void sparse_attn(const u16* __restrict__ Q,
                                                   const u16* __restrict__ Kmat,
                                                   const u16* __restrict__ Vt,
                                                   const int* __restrict__ rnd,
                                                   u16* __restrict__ Out) {
    __shared__ __align__(16) u16 Ks[3][8192];      // 48 KiB
    __shared__ __align__(16) char Plds[4 * 2048];  // 8 KiB

    const int qb = blockIdx.x, h = blockIdx.y;
    const int t = threadIdx.x, w = t >> 6, l = t & 63;
    const int lg = l >> 4, ll = l & 15;

    int blist[6];
    int nblk = 0;
    {
        int cands[6];
        cands[0] = qb - 1; cands[1] = qb; cands[2] = qb + 1;
        cands[3] = 0; cands[4] = NBLK - 1; cands[5] = rnd[qb];
        for (int c = 0; c < 6; ++c) {
            int b = cands[c];
            if (b < 0 || b >= NBLK) continue;
            bool dup = false;
            for (int j = 0; j < nblk; ++j) dup = dup || (blist[j] == b);
            if (!dup) blist[nblk++] = b;
        }
    }

    // stage one K tile (64 rows x 128 d), chunk-XOR swizzle on the global source
    auto stageK = [&](int sb, int kb) {
        const u16* kbase = Kmat + (size_t)(kb * 64) * HID + h * HD;
#pragma unroll
        for (int j = 0; j < 4; ++j) {
            int d = j * 256 + t;
            int kr = d >> 4, kc_ = (d & 15) ^ (kr & 7);
            gload_lds16(kbase + (size_t)kr * HID + kc_ * 8, &Ks[sb][d * 8]);
        }
    };

    bf16x8 qf[4];
    const int qrow = qb * 64 + w * 16 + ll;
#pragma unroll
    for (int kc = 0; kc < 4; ++kc)
        qf[kc] = *(const bf16x8*)&Q[(size_t)qrow * HID + h * HD + kc * 32 + lg * 8];

    f32x4 o[8];
#pragma unroll
    for (int dt = 0; dt < 8; ++dt) o[dt] = (f32x4){0.f, 0.f, 0.f, 0.f};
    float mrun[4], lrun[4];
#pragma unroll
    for (int r = 0; r < 4; ++r) { mrun[r] = -1e30f; lrun[r] = 0.f; }

    char* Pw = Plds + w * 2048;

    stageK(0, blist[0]);
    if (nblk > 1) stageK(1, blist[1]);
    int buf = 0;

    for (int bi = 0; bi < nblk; ++bi) {
        const int kb = blist[bi];
        const bool st = (bi + 2) < nblk;
        const int sb = (buf + 2 >= 3) ? buf - 1 : buf + 2;
        if (st) {
            stageK(sb, blist[bi + 2]);
            asm volatile("s_waitcnt vmcnt(8)" ::: "memory");   // K(bi) landed
        } else if (bi + 1 < nblk) {
            asm volatile("s_waitcnt vmcnt(4)" ::: "memory");
        } else {
            asm volatile("s_waitcnt vmcnt(0)" ::: "memory");
        }
        __builtin_amdgcn_s_barrier();

        // V reg-prefetch for this block (16x global_load_dwordx4, consumed at PV)
        bf16x8 vf[16];
#pragma unroll
        for (int kc2 = 0; kc2 < 2; ++kc2)
#pragma unroll
            for (int dt = 0; dt < 8; ++dt)
                vf[kc2 * 8 + dt] = *(const bf16x8*)&Vt[(size_t)(h * HD + dt * 16 + ll) * SEQQ +
                                                       kb * 64 + kc2 * 32 + lg * 8];

        // S = Q K^T
        f32x4 s[4];
#pragma unroll
        for (int ct = 0; ct < 4; ++ct) s[ct] = (f32x4){0.f, 0.f, 0.f, 0.f};
#pragma unroll
        for (int ct = 0; ct < 4; ++ct) {
            const int krow = ct * 16 + ll;
#pragma unroll
            for (int kc = 0; kc < 4; ++kc) {
                bf16x8 kf = *(const bf16x8*)&Ks[buf][krow * 128 +
                                                    (((kc * 4 + lg) ^ (krow & 7)) << 3)];
                s[ct] = __builtin_amdgcn_mfma_f32_16x16x32_bf16(qf[kc], kf, s[ct], 0, 0, 0);
            }
        }

        float rmax[4];
#pragma unroll
        for (int r = 0; r < 4; ++r) {
            s[0][r] *= ATT_SCALE; s[1][r] *= ATT_SCALE;
            s[2][r] *= ATT_SCALE; s[3][r] *= ATT_SCALE;
            rmax[r] = fmaxf(fmaxf(s[0][r], s[1][r]), fmaxf(s[2][r], s[3][r]));
        }
#pragma unroll
        for (int mk = 1; mk <= 8; mk <<= 1)
#pragma unroll
            for (int r = 0; r < 4; ++r)
                rmax[r] = fmaxf(rmax[r], __shfl_xor(rmax[r], mk));

        float scl[4], psum[4];
#pragma unroll
        for (int r = 0; r < 4; ++r) {
            float mn = fmaxf(mrun[r], rmax[r]);
            scl[r] = __expf(mrun[r] - mn);
            mrun[r] = mn;
            psum[r] = 0.f;
        }

#pragma unroll
        for (int ct = 0; ct < 4; ++ct)
#pragma unroll
            for (int r = 0; r < 4; ++r) {
                float e = __expf(s[ct][r] - mrun[r]);
                psum[r] += e;
                const int q = lg * 4 + r;
                const int kv = ct * 16 + ll;
                *(u16*)(Pw + q * 128 + ((kv * 2) ^ ((q & 7) << 4))) = f2bf(e);
            }
#pragma unroll
        for (int mk = 1; mk <= 8; mk <<= 1)
#pragma unroll
            for (int r = 0; r < 4; ++r)
                psum[r] += __shfl_xor(psum[r], mk);
#pragma unroll
        for (int r = 0; r < 4; ++r)
            lrun[r] = lrun[r] * scl[r] + psum[r];
#pragma unroll
        for (int dt = 0; dt < 8; ++dt)
#pragma unroll
            for (int r = 0; r < 4; ++r)
                o[dt][r] *= scl[r];

        // O += P @ V  (P from per-wave LDS, V from vf regs)
#pragma unroll
        for (int kc2 = 0; kc2 < 2; ++kc2) {
            bf16x8 pf = *(const bf16x8*)(Pw + ll * 128 +
                                         ((kc2 * 64 + lg * 16) ^ ((ll & 7) << 4)));
#pragma unroll
            for (int dt = 0; dt < 8; ++dt)
                o[dt] = __builtin_amdgcn_mfma_f32_16x16x32_bf16(pf, vf[kc2 * 8 + dt],
                                                                o[dt], 0, 0, 0);
        }

        __builtin_amdgcn_s_barrier();  // all waves done with Ks[buf] before reuse
        buf = (buf + 1 == 3) ? 0 : buf + 1;
    }

    float rl[4];
#pragma unroll
    for (int r = 0; r < 4; ++r) rl[r] = 1.f / lrun[r];
#pragma unroll
    for (int dt = 0; dt < 8; ++dt)
#pragma unroll
        for (int r = 0; r < 4; ++r) {
            int row = qb * 64 + w * 16 + lg * 4 + r;
            int col = h * HD + dt * 16 + ll;
            Out[(size_t)row * HID + col] = f2bf(o[dt][r] * rl[r]);
        }
}

// ---------------- launcher ----------------
extern "C" void kernel_launch(void* const* d_in, const int* in_sizes, int n_in,
                              void* d_out, int out_size, void* d_ws, size_t ws_size,
                              hipStream_t stream) {
    const float* hs = (const float*)d_in[0];
    const int* rnd = (const int*)d_in[1];
    const float* Wq = (const float*)d_in[2];
    const float* Wk = (const float*)d_in[3];
    const float* Wv = (const float*)d_in[4];
    const float* Wo = (const float*)d_in[5];
    float* out = (float*)d_out;

    char* ws = (char*)d_ws;
    u16* hs_b   = (u16*)(ws);                  // 16 MB
    u16* Wqkv_b = (u16*)(ws + 16777216);       // 24 MB
    u16* Wo_b   = (u16*)(ws + 41943040);       //  8 MB
    u16* Qb     = (u16*)(ws + 50331648);       // 16 MB
    u16* Kb     = (u16*)(ws + 67108864);       // 16 MB
    u16* Vtb    = (u16*)(ws + 83886080);       // 16 MB ([2048][4096])
    u16* Ab     = (u16*)(ws + 100663296);      // 16 MB (Vrow temp, then attn out)

    cvt_bf16_k<<<dim3(8192), 256, 0, stream>>>(hs, hs_b, 8388608 / 4);
    cvt4_k<<<dim3(4096, 4), 256, 0, stream>>>(Wq, Wk, Wv, Wo, Wqkv_b, Wo_b);

    // fused QKV: C[4096,6144] = hs @ [Wq;Wk;Wv]^T -> Qb, Kb, Vrow(Ab); 768 wgs = 3/CU
    gemm_p<1><<<dim3(24, 32), 512, 0, stream>>>(hs_b, Wqkv_b, Qb, Kb, Ab, 4096, 6144, 2048);

    transpose_k<<<dim3(64, 32), 256, 0, stream>>>(Ab, Vtb);

    sparse_attn<<<dim3(64, 16), 256, 0, stream>>>(Qb, Kb, Vtb, rnd, Ab);

    // Wo: 256 wgs = exactly 1/CU
    gemm_p<0><<<dim3(8, 32), 512, 0, stream>>>(Ab, Wo_b, out, nullptr, nullptr, 4096, 2048, 2048);
}